// Round 2
// baseline (846.809 us; speedup 1.0000x reference)
//
#include <hip/hip_runtime.h>
#include <hip/hip_bf16.h>

#define B_ 32
#define S_ 1024
#define D_ 512
#define H_ 8
#define DH_ 64
#define QBLK 128
#define KVB 64
#define NWAVE 8
#define NBLK 2048
#define NEGF (-1e30f)

using f32x4 = __attribute__((ext_vector_type(4))) float;
using bf16x8 = __attribute__((ext_vector_type(8))) short;

__device__ __forceinline__ unsigned short f2bf(float f) {
  union { float f; unsigned int u; } v;
  v.f = f;
  unsigned int r = v.u + 0x7fffu + ((v.u >> 16) & 1u);  // RNE, finite inputs
  return (unsigned short)(r >> 16);
}

__device__ __forceinline__ bf16x8 pack8(const float* __restrict__ p) {
  float4 a = *reinterpret_cast<const float4*>(p);
  float4 b = *reinterpret_cast<const float4*>(p + 4);
  bf16x8 r;
  r[0] = (short)f2bf(a.x); r[1] = (short)f2bf(a.y);
  r[2] = (short)f2bf(a.z); r[3] = (short)f2bf(a.w);
  r[4] = (short)f2bf(b.x); r[5] = (short)f2bf(b.y);
  r[6] = (short)f2bf(b.z); r[7] = (short)f2bf(b.w);
  return r;
}

__device__ __forceinline__ bf16x8 pack8r(float4 a, float4 b) {
  bf16x8 r;
  r[0] = (short)f2bf(a.x); r[1] = (short)f2bf(a.y);
  r[2] = (short)f2bf(a.z); r[3] = (short)f2bf(a.w);
  r[4] = (short)f2bf(b.x); r[5] = (short)f2bf(b.y);
  r[6] = (short)f2bf(b.z); r[7] = (short)f2bf(b.w);
  return r;
}

__device__ __forceinline__ f32x4 mfma16(bf16x8 a, bf16x8 b, f32x4 c) {
  return __builtin_amdgcn_mfma_f32_16x16x32_bf16(a, b, c, 0, 0, 0);
}

// swizzle: XOR bits 3-5 of the element index with (row ^ row>>3) — conflict-free
// scalar V-transpose writes (32 banks x 2-way-same-word) and 8-cycle-optimal b128 reads.
__device__ __forceinline__ int swz(int r) { return ((r ^ (r >> 3)) & 7) << 3; }

// ws[0:B*D) = sum_s v1 ; ws[B*D:2*B*D) = sum_s v2   (degenerate-row uniform softmax)
__global__ void colsum_kernel(const float* __restrict__ v1,
                              const float* __restrict__ v2,
                              float* __restrict__ ws) {
  const int b = blockIdx.x >> 4;
  const int chunk = blockIdx.x & 15;
  const int tid = threadIdx.x;
  const int dl = tid & 31;
  const int sg = tid >> 5;
  const int d = chunk * 32 + dl;
  float s1 = 0.f, s2 = 0.f;
  for (int s = sg; s < S_; s += 8) {
    size_t idx = ((size_t)b * S_ + s) * D_ + d;
    s1 += v1[idx];
    s2 += v2[idx];
  }
  __shared__ float r1[256], r2[256];
  r1[tid] = s1; r2[tid] = s2;
  __syncthreads();
  if (sg == 0) {
#pragma unroll
    for (int g = 1; g < 8; ++g) { s1 += r1[g * 32 + dl]; s2 += r2[g * 32 + dl]; }
    ws[b * D_ + d] = s1;
    ws[B_ * D_ + b * D_ + d] = s2;
  }
}

__global__ __launch_bounds__(512, 4) void attn_kernel(
    const float* __restrict__ qg, const float* __restrict__ kg,
    const float* __restrict__ v1g, const float* __restrict__ v2g,
    const int* __restrict__ cmask, const float* __restrict__ colsum,
    float* __restrict__ out) {
  // XCD-bijective swizzle: each XCD gets a contiguous chunk of logical ids (2048%8==0)
  const int wg = ((int)blockIdx.x & 7) * (NBLK / 8) + ((int)blockIdx.x >> 3);
  const int qb = wg & 7;
  const int h = (wg >> 3) & 7;
  const int b = wg >> 6;
  const int qt = qb * QBLK;
  const int tid = threadIdx.x;
  const int wid = tid >> 6;        // 0..7, wave owns rows qt+wid*16..+15
  const int lane = tid & 63;
  const int l15 = lane & 15;
  const int lg = lane >> 4;

  __shared__ alignas(16) unsigned short sK[KVB * 64];   // [kv][dh] swizzled
  __shared__ alignas(16) unsigned short sV1[KVB * 64];  // [dh][kv] swizzled
  __shared__ alignas(16) unsigned short sV2[KVB * 64];
  __shared__ alignas(16) unsigned short sP[NWAVE][16 * 64];
  __shared__ int sCnt[KVB];

  // Q fragments (A operand): row=l15, k = jk*32 + lg*8 + i
  bf16x8 qf[2];
  {
    const float* qp = qg + ((size_t)b * S_ + qt + wid * 16 + l15) * D_ + h * DH_;
#pragma unroll
    for (int jk = 0; jk < 2; ++jk) qf[jk] = pack8(qp + jk * 32 + lg * 8);
  }

  // staging: thread -> (row skv, cols sd0..sd0+7) of the 64x64 tile
  const int skv = tid >> 3;
  const int sd0 = (tid & 7) * 8;
  const int sKoff = skv * 64 + (sd0 ^ swz(skv));
  const size_t gbase = ((size_t)b * S_ + skv) * D_ + h * DH_ + sd0;

  float4 rK0, rK1, rV10, rV11, rV20, rV21;
  int rC = 1;
  auto issue = [&](int kv0) {
    const size_t o = gbase + (size_t)kv0 * D_;
    rK0 = *reinterpret_cast<const float4*>(kg + o);
    rK1 = *reinterpret_cast<const float4*>(kg + o + 4);
    rV10 = *reinterpret_cast<const float4*>(v1g + o);
    rV11 = *reinterpret_cast<const float4*>(v1g + o + 4);
    rV20 = *reinterpret_cast<const float4*>(v2g + o);
    rV21 = *reinterpret_cast<const float4*>(v2g + o + 4);
    if (tid < KVB) rC = cmask[b * S_ + kv0 + tid];
  };

  f32x4 o1[4], o2[4];
  float m_[4], l_[4];
#pragma unroll
  for (int i = 0; i < 4; ++i) {
    o1[i] = f32x4{0.f, 0.f, 0.f, 0.f};
    o2[i] = f32x4{0.f, 0.f, 0.f, 0.f};
    m_[i] = NEGF;
    l_[i] = 0.f;
  }

  const float SCL = 0.125f * 1.44269504089f;  // 1/sqrt(DH) * log2(e)
  const int ntile = 2 * qb + 2;
  issue(0);

  for (int ti = 0; ti < ntile; ++ti) {
    const int kv0 = ti * KVB;
    __syncthreads();  // all waves done reading LDS of prev tile (drain here is free)
    // ---- write staged regs -> LDS (fp32->bf16)
    {
      *reinterpret_cast<bf16x8*>(&sK[sKoff]) = pack8r(rK0, rK1);
      float ve[8];
      *reinterpret_cast<float4*>(&ve[0]) = rV10;
      *reinterpret_cast<float4*>(&ve[4]) = rV11;
#pragma unroll
      for (int e = 0; e < 8; ++e)
        sV1[(sd0 + e) * 64 + (skv ^ (((e ^ (tid & 7)) & 7) << 3))] = f2bf(ve[e]);
      *reinterpret_cast<float4*>(&ve[0]) = rV20;
      *reinterpret_cast<float4*>(&ve[4]) = rV21;
#pragma unroll
      for (int e = 0; e < 8; ++e)
        sV2[(sd0 + e) * 64 + (skv ^ (((e ^ (tid & 7)) & 7) << 3))] = f2bf(ve[e]);
      if (tid < KVB) sCnt[tid] = rC;
    }
    if (ti + 1 < ntile) issue(kv0 + KVB);  // in flight across the barrier below
    // barrier that does NOT drain vmcnt: LDS visibility only needs lgkmcnt(0)
    asm volatile("s_waitcnt lgkmcnt(0)" ::: "memory");
    __builtin_amdgcn_s_barrier();
    __builtin_amdgcn_sched_barrier(0);

    // wave-level skip: tile fully above this wave's strictly-causal diagonal
    if (kv0 <= qt + wid * 16 + 14) {
      // ---- S = Q.K^T (16q x 64k)
      f32x4 sa[4];
#pragma unroll
      for (int nb = 0; nb < 4; ++nb) {
        sa[nb] = f32x4{0.f, 0.f, 0.f, 0.f};
        const int key = nb * 16 + l15;
#pragma unroll
        for (int jk = 0; jk < 2; ++jk) {
          bf16x8 kf = *reinterpret_cast<const bf16x8*>(
              &sK[key * 64 + ((jk * 32 + lg * 8) ^ swz(key))]);
          sa[nb] = mfma16(qf[jk], kf, sa[nb]);
        }
      }
      // ---- mask + online softmax (log2 domain); C layout: col=l15, row=lg*4+r
#pragma unroll
      for (int r = 0; r < 4; ++r) {
        const int qrow = qt + wid * 16 + lg * 4 + r;
        const int prow = lg * 4 + r;
        float sv[4];
        float mx = NEGF;
#pragma unroll
        for (int nb = 0; nb < 4; ++nb) {
          const int key = kv0 + nb * 16 + l15;
          float s = sa[nb][r] * SCL;
          const bool ok = (key < qrow) && (sCnt[nb * 16 + l15] != 0);
          s = ok ? s : NEGF;
          sv[nb] = s;
          mx = fmaxf(mx, s);
        }
#pragma unroll
        for (int off = 1; off < 16; off <<= 1) mx = fmaxf(mx, __shfl_xor(mx, off));
        const float mnew = fmaxf(m_[r], mx);
        const float fac = exp2f(m_[r] - mnew);
        float rs = 0.f;
        const int swp = swz(prow);
#pragma unroll
        for (int nb = 0; nb < 4; ++nb) {
          const float p = exp2f(sv[nb] - mnew);
          rs += p;
          sP[wid][prow * 64 + ((nb * 16 + l15) ^ swp)] = f2bf(p);
        }
#pragma unroll
        for (int off = 1; off < 16; off <<= 1) rs += __shfl_xor(rs, off);
        l_[r] = l_[r] * fac + rs;
        m_[r] = mnew;
#pragma unroll
        for (int nd = 0; nd < 4; ++nd) { o1[nd][r] *= fac; o2[nd][r] *= fac; }
      }
      // ---- PV: O += P(16x64) . V(64x64)  (same-wave LDS RAW, no barrier)
      bf16x8 pa[2];
#pragma unroll
      for (int jk = 0; jk < 2; ++jk)
        pa[jk] = *reinterpret_cast<const bf16x8*>(
            &sP[wid][l15 * 64 + ((jk * 32 + lg * 8) ^ swz(l15))]);
#pragma unroll
      for (int nd = 0; nd < 4; ++nd) {
        const int drow = nd * 16 + l15;
        const int swd = swz(drow);
#pragma unroll
        for (int jk = 0; jk < 2; ++jk) {
          bf16x8 v1f = *reinterpret_cast<const bf16x8*>(
              &sV1[drow * 64 + ((jk * 32 + lg * 8) ^ swd)]);
          bf16x8 v2f = *reinterpret_cast<const bf16x8*>(
              &sV2[drow * 64 + ((jk * 32 + lg * 8) ^ swd)]);
          o1[nd] = mfma16(pa[jk], v1f, o1[nd]);
          o2[nd] = mfma16(pa[jk], v2f, o2[nd]);
        }
      }
    }
  }

  // ---- epilogue: normalize; degenerate rows = mean over ALL S keys
  float* outB = out + (size_t)B_ * S_ * D_;
  const size_t obase = (size_t)b * S_ * D_ + h * DH_;
#pragma unroll
  for (int r = 0; r < 4; ++r) {
    const int qrow = qt + wid * 16 + lg * 4 + r;
    const bool deg = (m_[r] <= -9.9e29f);
    const float invl = deg ? (1.0f / (float)S_) : (1.0f / l_[r]);
#pragma unroll
    for (int nd = 0; nd < 4; ++nd) {
      const int d = nd * 16 + l15;
      const float a1 = deg ? colsum[b * D_ + h * DH_ + d] : o1[nd][r];
      const float a2 = deg ? colsum[B_ * D_ + b * D_ + h * DH_ + d] : o2[nd][r];
      out[obase + (size_t)qrow * D_ + d] = a1 * invl;
      outB[obase + (size_t)qrow * D_ + d] = a2 * invl;
    }
  }
}

extern "C" void kernel_launch(void* const* d_in, const int* in_sizes, int n_in,
                              void* d_out, int out_size, void* d_ws, size_t ws_size,
                              hipStream_t stream) {
  const float* q = (const float*)d_in[0];
  const float* k = (const float*)d_in[1];
  const float* v1 = (const float*)d_in[2];
  const float* v2 = (const float*)d_in[3];
  const int* cm = (const int*)d_in[4];
  float* out = (float*)d_out;
  float* ws = (float*)d_ws;  // 2*B*D*4 = 128 KiB

  colsum_kernel<<<dim3(B_ * 16), dim3(256), 0, stream>>>(v1, v2, ws);
  attn_kernel<<<dim3(NBLK), dim3(512), 0, stream>>>(q, k, v1, v2, cm, ws, out);
}

// Round 3
// 402.257 us; speedup vs baseline: 2.1051x; 2.1051x over previous
//
#include <hip/hip_runtime.h>
#include <hip/hip_bf16.h>
#include <type_traits>

#define B_ 32
#define S_ 1024
#define D_ 512
#define H_ 8
#define DH_ 64
#define QBLK 128
#define KVB 64
#define NWAVE 8
#define NBLK 2048
#define NEGF (-1e30f)

using f32x4 = __attribute__((ext_vector_type(4))) float;
using bf16x8 = __attribute__((ext_vector_type(8))) short;

__device__ __forceinline__ unsigned short f2bf(float f) {
  union { float f; unsigned int u; } v;
  v.f = f;
  unsigned int r = v.u + 0x7fffu + ((v.u >> 16) & 1u);  // RNE, finite inputs
  return (unsigned short)(r >> 16);
}

__device__ __forceinline__ bf16x8 pack8(const float* __restrict__ p) {
  float4 a = *reinterpret_cast<const float4*>(p);
  float4 b = *reinterpret_cast<const float4*>(p + 4);
  bf16x8 r;
  r[0] = (short)f2bf(a.x); r[1] = (short)f2bf(a.y);
  r[2] = (short)f2bf(a.z); r[3] = (short)f2bf(a.w);
  r[4] = (short)f2bf(b.x); r[5] = (short)f2bf(b.y);
  r[6] = (short)f2bf(b.z); r[7] = (short)f2bf(b.w);
  return r;
}

__device__ __forceinline__ bf16x8 pack8r(float4 a, float4 b) {
  bf16x8 r;
  r[0] = (short)f2bf(a.x); r[1] = (short)f2bf(a.y);
  r[2] = (short)f2bf(a.z); r[3] = (short)f2bf(a.w);
  r[4] = (short)f2bf(b.x); r[5] = (short)f2bf(b.y);
  r[6] = (short)f2bf(b.z); r[7] = (short)f2bf(b.w);
  return r;
}

__device__ __forceinline__ f32x4 mfma16(bf16x8 a, bf16x8 b, f32x4 c) {
  return __builtin_amdgcn_mfma_f32_16x16x32_bf16(a, b, c, 0, 0, 0);
}

// XOR-swizzle bits 3..5 of the element index with (row ^ row>>3):
// conflict-light writes, 8-cycle-optimal b128 reads. Bit 0 untouched (b32 pairs ok).
__device__ __forceinline__ int swz(int r) { return ((r ^ (r >> 3)) & 7) << 3; }

__global__ __launch_bounds__(512, 3) void attn_kernel(
    const float* __restrict__ qg, const float* __restrict__ kg,
    const float* __restrict__ v1g, const float* __restrict__ v2g,
    const int* __restrict__ cmask, float* __restrict__ out) {
  // XCD-bijective swizzle (2048 % 8 == 0): contiguous chunk per XCD
  const int wg = ((int)blockIdx.x & 7) * (NBLK / 8) + ((int)blockIdx.x >> 3);
  const int qb = wg & 7;
  const int h = (wg >> 3) & 7;
  const int b = wg >> 6;
  const int qt = qb * QBLK;
  const int tid = threadIdx.x;
  const int wid = tid >> 6;        // wave owns q rows qt+wid*16 .. +15
  const int lane = tid & 63;
  const int l15 = lane & 15;
  const int lg = lane >> 4;

  __shared__ alignas(16) unsigned short sK[2][KVB * 64];   // [kv][dh] swizzled
  __shared__ alignas(16) unsigned short sV1[2][KVB * 64];  // [dh][kv] swizzled
  __shared__ alignas(16) unsigned short sV2[2][KVB * 64];
  __shared__ alignas(16) unsigned short sP[NWAVE][16 * 64];
  __shared__ int sCnt[2][KVB];

  // Q fragments (A operand): row=l15, k = jk*32 + lg*8 + i
  bf16x8 qf[2];
  {
    const float* qp = qg + ((size_t)b * S_ + qt + wid * 16 + l15) * D_ + h * DH_;
#pragma unroll
    for (int jk = 0; jk < 2; ++jk) qf[jk] = pack8(qp + jk * 32 + lg * 8);
  }

  // --- staging partitions ---
  // K: thread -> (row skv, 8 cols sd0..sd0+7), one b128 LDS write
  const int skv = tid >> 3;
  const int sd0 = (tid & 7) * 8;
  const int sKoff = skv * 64 + (sd0 ^ swz(skv));
  const size_t gK = ((size_t)b * S_ + skv) * D_ + h * DH_ + sd0;
  // V: thread -> (kv pair kvE,kvE+1, dh quad dq..dq+3), 4 packed b32 writes per V
  const int kvE = (tid >> 4) * 2;
  const int dq = (tid & 15) * 4;
  const size_t gV = ((size_t)b * S_ + kvE) * D_ + h * DH_ + dq;

  float4 rK0, rK1, rV1a, rV1b, rV2a, rV2b;
  int rC = 1;
  auto issue = [&](int kv0) {
    const size_t oK = gK + (size_t)kv0 * D_;
    rK0 = *reinterpret_cast<const float4*>(kg + oK);
    rK1 = *reinterpret_cast<const float4*>(kg + oK + 4);
    const size_t oV = gV + (size_t)kv0 * D_;
    rV1a = *reinterpret_cast<const float4*>(v1g + oV);
    rV1b = *reinterpret_cast<const float4*>(v1g + oV + D_);
    rV2a = *reinterpret_cast<const float4*>(v2g + oV);
    rV2b = *reinterpret_cast<const float4*>(v2g + oV + D_);
    if (tid < KVB) rC = cmask[b * S_ + kv0 + tid];
  };

  auto stage_write = [&](int buf) {
    *reinterpret_cast<bf16x8*>(&sK[buf][sKoff]) = pack8r(rK0, rK1);
    const float* a1 = reinterpret_cast<const float*>(&rV1a);
    const float* b1 = reinterpret_cast<const float*>(&rV1b);
    const float* a2 = reinterpret_cast<const float*>(&rV2a);
    const float* b2 = reinterpret_cast<const float*>(&rV2b);
#pragma unroll
    for (int e = 0; e < 4; ++e) {
      const int d = dq + e;
      const int off = d * 64 + (kvE ^ swz(d));  // kvE even; swz has no bit0
      unsigned int p1 = (unsigned int)f2bf(a1[e]) | ((unsigned int)f2bf(b1[e]) << 16);
      unsigned int p2 = (unsigned int)f2bf(a2[e]) | ((unsigned int)f2bf(b2[e]) << 16);
      *reinterpret_cast<unsigned int*>(&sV1[buf][off]) = p1;
      *reinterpret_cast<unsigned int*>(&sV2[buf][off]) = p2;
    }
    if (tid < KVB) sCnt[buf][tid] = rC;
  };

  f32x4 o1[4], o2[4];
  float m_[4], l_[4];
#pragma unroll
  for (int i = 0; i < 4; ++i) {
    o1[i] = f32x4{0.f, 0.f, 0.f, 0.f};
    o2[i] = f32x4{0.f, 0.f, 0.f, 0.f};
    m_[i] = NEGF;
    l_[i] = 0.f;
  }

  const float SCL = 0.125f * 1.44269504089f;  // 1/sqrt(DH) * log2(e)

  auto tile_compute = [&](int buf, int kv0, auto fullc) {
    constexpr bool FULL = decltype(fullc)::value;
    // ---- S = Q.K^T (16q x 64k)
    f32x4 sa[4];
#pragma unroll
    for (int nb = 0; nb < 4; ++nb) {
      sa[nb] = f32x4{0.f, 0.f, 0.f, 0.f};
      const int key = nb * 16 + l15;
#pragma unroll
      for (int jk = 0; jk < 2; ++jk) {
        bf16x8 kf = *reinterpret_cast<const bf16x8*>(
            &sK[buf][key * 64 + ((jk * 32 + lg * 8) ^ swz(key))]);
        sa[nb] = mfma16(qf[jk], kf, sa[nb]);
      }
    }
    // counter mask, hoisted out of the r-loop
    int cOK[4];
#pragma unroll
    for (int nb = 0; nb < 4; ++nb) cOK[nb] = sCnt[buf][nb * 16 + l15];

    // ---- mask + online softmax (log2 domain); C layout: col=l15, row=lg*4+r
#pragma unroll
    for (int r = 0; r < 4; ++r) {
      const int qrow = qt + wid * 16 + lg * 4 + r;
      const int prow = lg * 4 + r;
      float sv[4];
      float mx = NEGF;
#pragma unroll
      for (int nb = 0; nb < 4; ++nb) {
        const int key = kv0 + nb * 16 + l15;
        float s = sa[nb][r] * SCL;
        const bool ok = (cOK[nb] != 0) && (FULL || key < qrow);
        s = ok ? s : NEGF;
        sv[nb] = s;
        mx = fmaxf(mx, s);
      }
#pragma unroll
      for (int off = 1; off < 16; off <<= 1) mx = fmaxf(mx, __shfl_xor(mx, off));
      const float mnew = fmaxf(m_[r], mx);
      const float fac = exp2f(m_[r] - mnew);  // 1 while degenerate, 0 on first real key
      float rs = 0.f;
      const int swp = swz(prow);
#pragma unroll
      for (int nb = 0; nb < 4; ++nb) {
        const float p = exp2f(sv[nb] - mnew);
        rs += p;
        sP[wid][prow * 64 + ((nb * 16 + l15) ^ swp)] = f2bf(p);
      }
#pragma unroll
      for (int off = 1; off < 16; off <<= 1) rs += __shfl_xor(rs, off);
      l_[r] = l_[r] * fac + rs;
      m_[r] = mnew;
#pragma unroll
      for (int nd = 0; nd < 4; ++nd) { o1[nd][r] *= fac; o2[nd][r] *= fac; }
    }
    // ---- PV: O += P(16x64) . V(64x64)  (same-wave LDS RAW, no barrier)
    bf16x8 pa[2];
#pragma unroll
    for (int jk = 0; jk < 2; ++jk)
      pa[jk] = *reinterpret_cast<const bf16x8*>(
          &sP[wid][l15 * 64 + ((jk * 32 + lg * 8) ^ swz(l15))]);
#pragma unroll
    for (int nd = 0; nd < 4; ++nd) {
      const int drow = nd * 16 + l15;
      const int swd = swz(drow);
#pragma unroll
      for (int jk = 0; jk < 2; ++jk) {
        bf16x8 v1f = *reinterpret_cast<const bf16x8*>(
            &sV1[buf][drow * 64 + ((jk * 32 + lg * 8) ^ swd)]);
        bf16x8 v2f = *reinterpret_cast<const bf16x8*>(
            &sV2[buf][drow * 64 + ((jk * 32 + lg * 8) ^ swd)]);
        o1[nd] = mfma16(pa[jk], v1f, o1[nd]);
        o2[nd] = mfma16(pa[jk], v2f, o2[nd]);
      }
    }
  };

  const int ntile = 2 * qb + 2;
  issue(0);
  for (int ti = 0; ti < ntile; ++ti) {
    const int kv0 = ti * KVB;
    const int buf = ti & 1;
    stage_write(buf);                       // implicit vmcnt wait on own loads
    if (ti + 1 < ntile) issue(kv0 + KVB);   // stays in flight across the barrier
    asm volatile("s_waitcnt lgkmcnt(0)" ::: "memory");
    __builtin_amdgcn_s_barrier();           // single barrier/tile (dbuf makes WAR safe)
    __builtin_amdgcn_sched_barrier(0);
    if (kv0 <= qt + wid * 16 + 14) {        // wave-level causal skip
      if (kv0 + KVB <= qt + wid * 16)
        tile_compute(buf, kv0, std::integral_constant<bool, true>{});
      else
        tile_compute(buf, kv0, std::integral_constant<bool, false>{});
    }
  }

  // ---- epilogue: normalize; degenerate rows = mean of v over ALL S keys.
  // Only waves that actually contain a degenerate row pay for the column sums.
  bool degr[4];
  bool any = false;
#pragma unroll
  for (int r = 0; r < 4; ++r) { degr[r] = (m_[r] <= -9.9e29f); any |= degr[r]; }
  float cs1[4] = {0.f, 0.f, 0.f, 0.f}, cs2[4] = {0.f, 0.f, 0.f, 0.f};
  if (__any(any)) {
    float c1 = 0.f, c2 = 0.f;  // column sums for d = lane (coalesced 256B/row)
    const float* pv1 = v1g + (size_t)b * S_ * D_ + h * DH_ + lane;
    const float* pv2 = v2g + (size_t)b * S_ * D_ + h * DH_ + lane;
#pragma unroll 4
    for (int s = 0; s < S_; ++s) {
      c1 += pv1[(size_t)s * D_];
      c2 += pv2[(size_t)s * D_];
    }
#pragma unroll
    for (int nd = 0; nd < 4; ++nd) {
      cs1[nd] = __shfl(c1, nd * 16 + l15);
      cs2[nd] = __shfl(c2, nd * 16 + l15);
    }
  }

  float* outB = out + (size_t)B_ * S_ * D_;
  const size_t obase = (size_t)b * S_ * D_ + h * DH_;
#pragma unroll
  for (int r = 0; r < 4; ++r) {
    const int qrow = qt + wid * 16 + lg * 4 + r;
    const float invl = degr[r] ? (1.0f / (float)S_) : (1.0f / l_[r]);
#pragma unroll
    for (int nd = 0; nd < 4; ++nd) {
      const int d = nd * 16 + l15;
      const float a1 = degr[r] ? cs1[nd] : o1[nd][r];
      const float a2 = degr[r] ? cs2[nd] : o2[nd][r];
      out[obase + (size_t)qrow * D_ + d] = a1 * invl;
      outB[obase + (size_t)qrow * D_ + d] = a2 * invl;
    }
  }
}

extern "C" void kernel_launch(void* const* d_in, const int* in_sizes, int n_in,
                              void* d_out, int out_size, void* d_ws, size_t ws_size,
                              hipStream_t stream) {
  const float* q = (const float*)d_in[0];
  const float* k = (const float*)d_in[1];
  const float* v1 = (const float*)d_in[2];
  const float* v2 = (const float*)d_in[3];
  const int* cm = (const int*)d_in[4];
  float* out = (float*)d_out;

  attn_kernel<<<dim3(NBLK), dim3(512), 0, stream>>>(q, k, v1, v2, cm, out);
}